// Round 10
// baseline (1181.236 us; speedup 1.0000x reference)
//
#include <hip/hip_runtime.h>
#include <hip/hip_bf16.h>

#define TOKENS 32768
#define NEXP   16
#define HID    2048
#define IMD    1408
#define BM 256
#define BK 64

typedef __bf16 bf16x8 __attribute__((ext_vector_type(8)));
typedef float  f32x4  __attribute__((ext_vector_type(4)));
typedef float  f32x16 __attribute__((ext_vector_type(16)));
typedef unsigned short u16x8 __attribute__((ext_vector_type(8)));

using gptr1_t = const __attribute__((address_space(1))) void*;
using lptr3_t = __attribute__((address_space(3))) void*;

static __device__ __forceinline__ unsigned short f2bf(float f) {
  unsigned int x = __builtin_bit_cast(unsigned int, f);
  x += 0x7fffu + ((x >> 16) & 1u);   // round-to-nearest-even
  return (unsigned short)(x >> 16);
}
static __device__ __forceinline__ void gload16(const void* g, void* l) {
  __builtin_amdgcn_global_load_lds((gptr1_t)g, (lptr3_t)l, 16, 0, 0);
}
static __device__ __forceinline__ void vwait0() {
  asm volatile("s_waitcnt vmcnt(0)" ::: "memory");
}
static __device__ __forceinline__ void lgkm4() {
  asm volatile("s_waitcnt lgkmcnt(4)" ::: "memory");
}
static __device__ __forceinline__ void lgkm0() {
  asm volatile("s_waitcnt lgkmcnt(0)" ::: "memory");
}
// raw LDS read: we own the lgkmcnt discipline (rule 18: sched_barrier after waits)
static __device__ __forceinline__ f32x4 ds128(unsigned addr) {
  f32x4 d;
  asm volatile("ds_read_b128 %0, %1" : "=&v"(d) : "v"(addr));
  return d;
}

// ---------------- f32 -> bf16 straight convert (x) ----------------
__global__ __launch_bounds__(256)
void convert_kernel(const float* __restrict__ in, unsigned short* __restrict__ out, size_t n)
{
  size_t i = ((size_t)blockIdx.x * blockDim.x + threadIdx.x) * 8;
  if (i >= n) return;
  float4 a = *(const float4*)(in + i);
  float4 b = *(const float4*)(in + i + 4);
  u16x8 o;
  o[0] = f2bf(a.x); o[1] = f2bf(a.y); o[2] = f2bf(a.z); o[3] = f2bf(a.w);
  o[4] = f2bf(b.x); o[5] = f2bf(b.y); o[6] = f2bf(b.z); o[7] = f2bf(b.w);
  *(u16x8*)(out + i) = o;
}

// ------------- f32 [E][K][N] -> bf16 [E][N][K] transpose-convert -------------
__global__ __launch_bounds__(256)
void transpose_conv_kernel(const float* __restrict__ in, unsigned short* __restrict__ out,
                           int K, int N)
{
  __shared__ float tile[32][33];
  const int e = blockIdx.z;
  const float* ip = in + (size_t)e * K * N;
  unsigned short* op = out + (size_t)e * K * N;
  const int c0 = blockIdx.x * 32, r0 = blockIdx.y * 32;
  const int tx = threadIdx.x, ty = threadIdx.y;
#pragma unroll
  for (int i = 0; i < 4; ++i)
    tile[ty + 8 * i][tx] = ip[(size_t)(r0 + ty + 8 * i) * N + c0 + tx];
  __syncthreads();
#pragma unroll
  for (int i = 0; i < 4; ++i)
    op[(size_t)(c0 + ty + 8 * i) * K + r0 + tx] = f2bf(tile[tx][ty + 8 * i]);
}

// ======== grouped GEMM, 256x256, BK=64, 32x32x16, A-via-LDS / B-DIRECT-L2 ====
// r6 base (fastest) with B removed from LDS: b-fragments load straight from
// global (L2-resident panel) into registers — identical data mapping to r6's
// LDS path (lane: col wc*32+l31, k = kk*16 + hi*8 .. +8). Removes per CU-tile
// 64KB ds_read service + 32KB DMA from the contended LDS unit (additive-cost
// model, r8/r9 evidence). A staging/swizzle/epilogue byte-identical to r6.
// MODE 0: fused gate+up (acc[.][0]=gate from B0m, acc[.][1]=up from B1m):
//         h = bf16(silu(g)*u). MODE 1: down, BN=256, f32 out.
template<int MODE, int K, int N>
__global__ __launch_bounds__(512, 2)
void gemm_kernel(const unsigned short* __restrict__ A,
                 const unsigned short* __restrict__ B0m,
                 const unsigned short* __restrict__ B1m,
                 unsigned short* __restrict__ Hc,
                 float* __restrict__ Cf,
                 const int* __restrict__ gs)
{
  constexpr int NRT = TOKENS / BM;   // 128 row tiles
  constexpr int nt  = K / BK;        // 32 (MODE0) / 22 (MODE1)

  __shared__ __align__(16) unsigned short lA[2][256 * 64];  // 64 KiB (A only)

  // bijective XCD swizzle; row-tile fastest -> per-XCD chunk shares a B panel
  const int nwg = gridDim.x;
  const int qq = nwg >> 3;
  const int wgid = (blockIdx.x & 7) * qq + (blockIdx.x >> 3);
  const int rt = wgid % NRT;
  const int ct = wgid / NRT;
  const int row0 = rt * BM;

  int e = 0;
  { int a0 = 0;
    for (int i = 0; i < NEXP; ++i) { int s = gs[i]; if (row0 < a0 + s) { e = i; break; } a0 += s; } }

  const unsigned short* Ap = A + (size_t)row0 * K;
  const unsigned short* Bg = B0m + (size_t)e * N * K;
  const unsigned short* Bu = (MODE == 0) ? (B1m + (size_t)e * N * K) : nullptr;

  const int tid  = threadIdx.x;
  const int lane = tid & 63, wave = tid >> 6;
  const int wr = wave >> 2, wc = wave & 3;   // 2 M-waves x 4 N-waves, 128x64/wave
  const int l31 = lane & 31, hi = lane >> 5, l7 = lane & 7;
  const int r8 = lane >> 3;
  const int slog = ((lane & 7) ^ r8) * 8;    // pre-swizzled staging source column

  // swizzled A-read slot byte-offsets per kk: slot = (kk*2+hi) ^ (row&7=l7)
  const unsigned sw0 = (unsigned)(((0 + hi) ^ l7) * 16);
  const unsigned sw1 = (unsigned)(((2 + hi) ^ l7) * 16);
  const unsigned sw2 = (unsigned)(((4 + hi) ^ l7) * 16);
  const unsigned sw3 = (unsigned)(((6 + hi) ^ l7) * 16);

  const unsigned lAb = (unsigned)(unsigned long long)(const void*)&lA[0][0];
  const unsigned aRow = lAb + (unsigned)((wr * 128 + l31) * 128);  // 128B rows

  // B direct-load pointers (per lane; elements). Matches r6's LDS-fed mapping.
  const unsigned short* bP0;
  const unsigned short* bP1;
  if constexpr (MODE == 0) {
    const int col = ct * 128 + wc * 32 + l31;
    bP0 = Bg + (size_t)col * K + hi * 8;   // gate
    bP1 = Bu + (size_t)col * K + hi * 8;   // up
  } else {
    bP0 = Bg + (size_t)(ct * 256 + wc * 64 + l31) * K + hi * 8;
    bP1 = bP0 + (size_t)32 * K;
  }

  f32x16 acc[4][2] = {};

  // A staging: one chunk = 128 rows; 2 gload16/thread; chunks c=0 (rows 0..127)
  // and c=1 (rows 128..255), identity row layout, pre-swizzled source (slog).
  auto stageA = [&](int tt) {
    const int buf = tt & 1;
    const int k0 = tt * BK;
#pragma unroll
    for (int c = 0; c < 2; ++c)
#pragma unroll
      for (int w = 0; w < 2; ++w) {
        unsigned short* ldst = &lA[buf][(c * 128 + w * 64 + wave * 8) * 64];
        const int grow = c * 128 + w * 64 + wave * 8 + r8;
        gload16(Ap + (size_t)grow * K + k0 + slog, ldst);
      }
  };

  auto rdA = [&](f32x4* d, unsigned sw, unsigned bufoff) {
#pragma unroll
    for (int m = 0; m < 4; ++m)
      d[m] = ds128(aRow + bufoff + (unsigned)(m * 4096) + sw);
  };
  auto cluster = [&](const f32x4* a4, f32x4 bgv, f32x4 buv) {
    __builtin_amdgcn_sched_barrier(0);
    __builtin_amdgcn_s_setprio(1);
#pragma unroll
    for (int m = 0; m < 4; ++m) {
      acc[m][0] = __builtin_amdgcn_mfma_f32_32x32x16_bf16(
          __builtin_bit_cast(bf16x8, a4[m]), __builtin_bit_cast(bf16x8, bgv),
          acc[m][0], 0, 0, 0);
      acc[m][1] = __builtin_amdgcn_mfma_f32_32x32x16_bf16(
          __builtin_bit_cast(bf16x8, a4[m]), __builtin_bit_cast(bf16x8, buv),
          acc[m][1], 0, 0, 0);
    }
    __builtin_amdgcn_s_setprio(0);
    __builtin_amdgcn_sched_barrier(0);
  };

  // prologue: A tile 0 staged and published
  stageA(0);
  vwait0();
  __builtin_amdgcn_s_barrier();

  f32x4 aS0[4], aS1[4], aS2[4];

#pragma unroll 1
  for (int t = 0; t < nt; ++t) {
    const unsigned bufoff = (unsigned)((t & 1) * 32768);
    const bool more = (t + 1 < nt);
    const int bo = t * 64;   // element offset of this K-tile in B rows

    // B half 1: kk0, kk1 (consumed ~200+cy later; L2-resident panel)
    f32x4 bg0 = *(const f32x4*)(bP0 + bo);
    f32x4 bu0 = *(const f32x4*)(bP1 + bo);
    f32x4 bg1 = *(const f32x4*)(bP0 + bo + 16);
    f32x4 bu1 = *(const f32x4*)(bP1 + bo + 16);
    if (more) stageA(t + 1);                        // 4x gload16 -> lA[buf^1]

    rdA(aS0, sw0, bufoff);                          // kk0
    rdA(aS1, sw1, bufoff);                          // kk1
    lgkm4();                                        // kk0 ready, kk1 in flight
    cluster(aS0, bg0, bu0);                         // kk0
    // B half 2: kk2, kk3 (cover = cluster kk1 + reads ~300cy)
    f32x4 bg2 = *(const f32x4*)(bP0 + bo + 32);
    f32x4 bu2 = *(const f32x4*)(bP1 + bo + 32);
    f32x4 bg3 = *(const f32x4*)(bP0 + bo + 48);
    f32x4 bu3 = *(const f32x4*)(bP1 + bo + 48);
    rdA(aS2, sw2, bufoff);                          // kk2
    lgkm4();                                        // kk1 ready
    cluster(aS1, bg1, bu1);                         // kk1
    rdA(aS0, sw3, bufoff);                          // kk3 (reuse set 0)
    lgkm4();                                        // kk2 ready
    cluster(aS2, bg2, bu2);                         // kk2
    lgkm0();                                        // kk3 ready
    cluster(aS0, bg3, bu3);                         // kk3

    if (more) {
      vwait0();                                     // own A-DMA(t+1) landed
      __builtin_amdgcn_s_barrier();                 // publish lA[buf^1]
    }
  }

  // epilogue. 32x32 C/D layout (m74/m101): col = lane&31,
  // row = (reg&3) + 8*(reg>>2) + 4*(lane>>5)   [r6-verified on this problem]
#pragma unroll
  for (int m = 0; m < 4; ++m) {
    const int rowb = row0 + wr * 128 + m * 32 + 4 * hi;
    if constexpr (MODE == 0) {
      const int col = ct * 128 + wc * 32 + l31;
      f32x16 g = acc[m][0], u = acc[m][1];
#pragma unroll
      for (int r = 0; r < 16; ++r) {
        const int row = rowb + (r & 3) + 8 * (r >> 2);
        float gv = g[r];
        float s = gv / (1.f + __expf(-gv)) * u[r];
        Hc[(size_t)row * N + col] = f2bf(s);
      }
    } else {
#pragma unroll
      for (int n2 = 0; n2 < 2; ++n2) {
        const int col = ct * 256 + wc * 64 + n2 * 32 + l31;
        f32x16 v = acc[m][n2];
#pragma unroll
        for (int r = 0; r < 16; ++r) {
          const int row = rowb + (r & 3) + 8 * (r >> 2);
          Cf[(size_t)row * N + col] = v[r];
        }
      }
    }
  }
}

extern "C" void kernel_launch(void* const* d_in, const int* in_sizes, int n_in,
                              void* d_out, int out_size, void* d_ws, size_t ws_size,
                              hipStream_t stream)
{
  const float* x  = (const float*)d_in[0];
  const float* wg = (const float*)d_in[1];
  const float* wu = (const float*)d_in[2];
  const float* wd = (const float*)d_in[3];
  const int*   gs = (const int*)d_in[4];
  float* out = (float*)d_out;

  const size_t SZ_XB = (size_t)TOKENS * HID * 2;
  const size_t SZ_W  = (size_t)NEXP * HID * IMD * 2;
  const size_t SZ_H  = (size_t)TOKENS * IMD * 2;
  if (ws_size < SZ_XB + 2 * SZ_W + SZ_H) return;

  char* ws = (char*)d_ws;
  unsigned short* xb  = (unsigned short*)ws;
  unsigned short* wTg = (unsigned short*)(ws + SZ_XB);
  unsigned short* wTu = (unsigned short*)(ws + SZ_XB + SZ_W);
  unsigned short* h   = (unsigned short*)(ws + SZ_XB + 2 * SZ_W);

  const int cvt_grid = (int)(((size_t)TOKENS * HID) / (256 * 8));
  convert_kernel<<<cvt_grid, 256, 0, stream>>>(x, xb, (size_t)TOKENS * HID);

  transpose_conv_kernel<<<dim3(IMD / 32, HID / 32, NEXP), dim3(32, 8), 0, stream>>>(wg, wTg, HID, IMD);
  transpose_conv_kernel<<<dim3(IMD / 32, HID / 32, NEXP), dim3(32, 8), 0, stream>>>(wu, wTu, HID, IMD);
  gemm_kernel<0, HID, IMD><<<(TOKENS / BM) * (IMD / 128), 512, 0, stream>>>(
      xb, wTg, wTu, h, nullptr, gs);

  transpose_conv_kernel<<<dim3(HID / 32, IMD / 32, NEXP), dim3(32, 8), 0, stream>>>(wd, wTg, IMD, HID);
  gemm_kernel<1, IMD, HID><<<(TOKENS / BM) * (HID / 256), 512, 0, stream>>>(
      h, wTg, nullptr, nullptr, out, gs);
}

// Round 11
// 867.856 us; speedup vs baseline: 1.3611x; 1.3611x over previous
//
#include <hip/hip_runtime.h>
#include <hip/hip_bf16.h>

#define TOKENS 32768
#define NEXP   16
#define HID    2048
#define IMD    1408
#define BM 256
#define BK 64

typedef __bf16 bf16x8 __attribute__((ext_vector_type(8)));
typedef float  f32x4  __attribute__((ext_vector_type(4)));
typedef float  f32x16 __attribute__((ext_vector_type(16)));
typedef unsigned short u16x8 __attribute__((ext_vector_type(8)));

using gptr1_t = const __attribute__((address_space(1))) void*;
using lptr3_t = __attribute__((address_space(3))) void*;

static __device__ __forceinline__ unsigned short f2bf(float f) {
  unsigned int x = __builtin_bit_cast(unsigned int, f);
  x += 0x7fffu + ((x >> 16) & 1u);   // round-to-nearest-even
  return (unsigned short)(x >> 16);
}
static __device__ __forceinline__ void gload16(const void* g, void* l) {
  __builtin_amdgcn_global_load_lds((gptr1_t)g, (lptr3_t)l, 16, 0, 0);
}
static __device__ __forceinline__ void vwait0() {
  asm volatile("s_waitcnt vmcnt(0)" ::: "memory");
}
static __device__ __forceinline__ void lgkm6() {
  asm volatile("s_waitcnt lgkmcnt(6)" ::: "memory");
}
static __device__ __forceinline__ void lgkm0() {
  asm volatile("s_waitcnt lgkmcnt(0)" ::: "memory");
}
// raw LDS read: we own the lgkmcnt discipline
static __device__ __forceinline__ f32x4 ds128(unsigned addr) {
  f32x4 d;
  asm volatile("ds_read_b128 %0, %1" : "=&v"(d) : "v"(addr));
  return d;
}

// ---------------- f32 -> bf16 straight convert (x) ----------------
__global__ __launch_bounds__(256)
void convert_kernel(const float* __restrict__ in, unsigned short* __restrict__ out, size_t n)
{
  size_t i = ((size_t)blockIdx.x * blockDim.x + threadIdx.x) * 8;
  if (i >= n) return;
  float4 a = *(const float4*)(in + i);
  float4 b = *(const float4*)(in + i + 4);
  u16x8 o;
  o[0] = f2bf(a.x); o[1] = f2bf(a.y); o[2] = f2bf(a.z); o[3] = f2bf(a.w);
  o[4] = f2bf(b.x); o[5] = f2bf(b.y); o[6] = f2bf(b.z); o[7] = f2bf(b.w);
  *(u16x8*)(out + i) = o;
}

// ------------- f32 [E][K][N] -> bf16 [E][N][K] transpose-convert -------------
__global__ __launch_bounds__(256)
void transpose_conv_kernel(const float* __restrict__ in, unsigned short* __restrict__ out,
                           int K, int N)
{
  __shared__ float tile[32][33];
  const int e = blockIdx.z;
  const float* ip = in + (size_t)e * K * N;
  unsigned short* op = out + (size_t)e * K * N;
  const int c0 = blockIdx.x * 32, r0 = blockIdx.y * 32;
  const int tx = threadIdx.x, ty = threadIdx.y;
#pragma unroll
  for (int i = 0; i < 4; ++i)
    tile[ty + 8 * i][tx] = ip[(size_t)(r0 + ty + 8 * i) * N + c0 + tx];
  __syncthreads();
#pragma unroll
  for (int i = 0; i < 4; ++i)
    op[(size_t)(c0 + ty + 8 * i) * K + r0 + tx] = f2bf(tile[tx][ty + 8 * i]);
}

// ======== grouped GEMM, 256x256 tile, BK=64, 32x32x16 MFMA (r6 structure) ====
// r6 verbatim except the block->tile mapping: XCD CHUNKING. Each XCD owns a
// contiguous 16-row-tile chunk (16.7MB of A, L3-resident; weights of only 2
// experts ~23MB) x all column tiles -> compulsory-traffic fetch instead of
// re-streaming A per column panel (r6 measured 811MB vs 318MB footprint).
// MODE 0: fused gate+up, B cols interleaved by 32 (g/u): h = bf16(silu(g)*u).
// MODE 1: down: Cf = acc (f32).
template<int MODE, int K, int N>
__global__ __launch_bounds__(512, 2)
void gemm_kernel(const unsigned short* __restrict__ A,
                 const unsigned short* __restrict__ B0m,
                 const unsigned short* __restrict__ B1m,
                 unsigned short* __restrict__ Hc,
                 float* __restrict__ Cf,
                 const int* __restrict__ gs)
{
  constexpr int NRT = TOKENS / BM;   // 128 row tiles
  constexpr int nt  = K / BK;

  __shared__ __align__(16) unsigned short lA[2][256 * 64];  // 64 KiB
  __shared__ __align__(16) unsigned short lB[2][256 * 64];  // 64 KiB

  // XCD chunking: xcd owns rt in [xcd*16, xcd*16+16) x all ct (bijective:
  // nwg/8 = 16*CTN exactly for both modes).
  const int xcd = blockIdx.x & 7;
  const int i   = blockIdx.x >> 3;
  const int rt  = xcd * (NRT / 8) + (i % (NRT / 8));
  const int ct  = i / (NRT / 8);
  const int row0 = rt * BM;

  int e = 0;
  { int a0 = 0;
    for (int ii = 0; ii < NEXP; ++ii) { int s = gs[ii]; if (row0 < a0 + s) { e = ii; break; } a0 += s; } }

  const unsigned short* Ap = A + (size_t)row0 * K;
  const unsigned short* Bg = B0m + (size_t)e * N * K;
  const unsigned short* Bu = (MODE == 0) ? (B1m + (size_t)e * N * K) : nullptr;

  const int tid  = threadIdx.x;
  const int lane = tid & 63, wave = tid >> 6;
  const int wr = wave >> 2, wc = wave & 3;   // 2 M-waves x 4 N-waves, 128x64/wave
  const int l31 = lane & 31, hi = lane >> 5, l7 = lane & 7;
  const int r8 = lane >> 3;
  const int slog = ((lane & 7) ^ r8) * 8;    // pre-swizzled staging source column

  // swizzled read slot byte-offsets per kk: slot = (kk*2+hi) ^ (row&7=l7)
  const unsigned sw0 = (unsigned)(((0 + hi) ^ l7) * 16);
  const unsigned sw1 = (unsigned)(((2 + hi) ^ l7) * 16);
  const unsigned sw2 = (unsigned)(((4 + hi) ^ l7) * 16);
  const unsigned sw3 = (unsigned)(((6 + hi) ^ l7) * 16);

  // LDS byte bases (low 32 bits of generic pointer = LDS offset)
  const unsigned lAb = (unsigned)(unsigned long long)(const void*)&lA[0][0];
  const unsigned lBb = (unsigned)(unsigned long long)(const void*)&lB[0][0];
  const unsigned aRow = lAb + (unsigned)((wr * 128 + l31) * 128);  // row stride 128B
  const unsigned bRow = lBb + (unsigned)((wc * 64 + l31) * 128);

  f32x16 acc[4][2] = {};

  // stage one 128-row chunk (2 x gload16/thread).
  // chunk: 0 = B rows 0..127, 1 = B rows 128..255, 2 = A rows 0..127, 3 = A 128..255
  auto stage = [&](int chunk, int tt) {
    const int buf = tt & 1;
    const int k0 = tt * BK;
#pragma unroll
    for (int w = 0; w < 2; ++w) {
      if (chunk >= 2) {
        const int c = chunk - 2;
        unsigned short* ldst = &lA[buf][(c * 128 + w * 64 + wave * 8) * 64];
        const int grow = c * 128 + w * 64 + wave * 8 + r8;
        gload16(Ap + (size_t)grow * K + k0 + slog, ldst);
      } else {
        unsigned short* ldst = &lB[buf][(chunk * 128 + w * 64 + wave * 8) * 64];
        const int rem = w * 64 + wave * 8 + r8;       // 0..127
        const int v = chunk * 128 + rem;              // B LDS row 0..255
        if constexpr (MODE == 0) {
          const int wcq = v >> 6, p = (v >> 5) & 1, ii = v & 31;
          const unsigned short* mb = p ? Bu : Bg;
          const int gcol = ct * 128 + wcq * 32 + ii;
          gload16(mb + (size_t)gcol * K + k0 + slog, ldst);
        } else {
          const int gcol = ct * 256 + v;
          gload16(Bg + (size_t)gcol * K + k0 + slog, ldst);
        }
      }
    }
  };

  auto rdA = [&](f32x4* d, unsigned sw, unsigned bufoff) {
#pragma unroll
    for (int m = 0; m < 4; ++m)
      d[m] = ds128(aRow + bufoff + (unsigned)(m * 4096) + sw);
  };
  auto rdB = [&](f32x4* d, unsigned sw, unsigned bufoff) {
    d[0] = ds128(bRow + bufoff + sw);
    d[1] = ds128(bRow + bufoff + 4096u + sw);
  };
  auto cluster = [&](const f32x4* a4, const f32x4* b2) {
    __builtin_amdgcn_sched_barrier(0);
    __builtin_amdgcn_s_setprio(1);
#pragma unroll
    for (int m = 0; m < 4; ++m)
#pragma unroll
      for (int n2 = 0; n2 < 2; ++n2)
        acc[m][n2] = __builtin_amdgcn_mfma_f32_32x32x16_bf16(
            __builtin_bit_cast(bf16x8, a4[m]), __builtin_bit_cast(bf16x8, b2[n2]),
            acc[m][n2], 0, 0, 0);
    __builtin_amdgcn_s_setprio(0);
    __builtin_amdgcn_sched_barrier(0);
  };

  // prologue: tile 0 staged and published
  stage(0, 0); stage(1, 0); stage(2, 0); stage(3, 0);
  vwait0();
  __builtin_amdgcn_s_barrier();

  f32x4 aS0[4], bS0[2], aS1[4], bS1[2], aS2[4], bS2[2];

#pragma unroll 1
  for (int t = 0; t < nt; ++t) {
    const unsigned bufoff = (unsigned)((t & 1) * 32768);
    const bool more = (t + 1 < nt);

    rdA(aS0, sw0, bufoff); rdB(bS0, sw0, bufoff);   // kk0
    rdA(aS1, sw1, bufoff); rdB(bS1, sw1, bufoff);   // kk1
    lgkm6();                                        // kk0 complete, kk1 in flight
    cluster(aS0, bS0);
    if (more) { stage(0, t + 1); stage(1, t + 1); }
    rdA(aS2, sw2, bufoff); rdB(bS2, sw2, bufoff);   // kk2
    lgkm6();                                        // kk1 complete
    cluster(aS1, bS1);
    if (more) { stage(2, t + 1); stage(3, t + 1); }
    rdA(aS0, sw3, bufoff); rdB(bS0, sw3, bufoff);   // kk3 (reuse set 0)
    lgkm6();                                        // kk2 complete
    cluster(aS2, bS2);
    lgkm0();                                        // kk3 complete
    cluster(aS0, bS0);

    vwait0();                                       // own t+1 stages landed
    __builtin_amdgcn_s_barrier();                   // publish LDS[t+1 buffer]
  }

  // epilogue. 32x32 C/D layout (m74/m101): col = lane&31,
  // row = (reg&3) + 8*(reg>>2) + 4*(lane>>5)
#pragma unroll
  for (int m = 0; m < 4; ++m) {
    const int rowb = row0 + wr * 128 + m * 32 + 4 * hi;
    if constexpr (MODE == 0) {
      const int col = ct * 128 + wc * 32 + l31;
      f32x16 g = acc[m][0], u = acc[m][1];
#pragma unroll
      for (int r = 0; r < 16; ++r) {
        const int row = rowb + (r & 3) + 8 * (r >> 2);
        float gv = g[r];
        float s = gv / (1.f + __expf(-gv)) * u[r];
        Hc[(size_t)row * N + col] = f2bf(s);
      }
    } else {
#pragma unroll
      for (int n2 = 0; n2 < 2; ++n2) {
        const int col = ct * 256 + wc * 64 + n2 * 32 + l31;
        f32x16 v = acc[m][n2];
#pragma unroll
        for (int r = 0; r < 16; ++r) {
          const int row = rowb + (r & 3) + 8 * (r >> 2);
          Cf[(size_t)row * N + col] = v[r];
        }
      }
    }
  }
}

extern "C" void kernel_launch(void* const* d_in, const int* in_sizes, int n_in,
                              void* d_out, int out_size, void* d_ws, size_t ws_size,
                              hipStream_t stream)
{
  const float* x  = (const float*)d_in[0];
  const float* wg = (const float*)d_in[1];
  const float* wu = (const float*)d_in[2];
  const float* wd = (const float*)d_in[3];
  const int*   gs = (const int*)d_in[4];
  float* out = (float*)d_out;

  const size_t SZ_XB = (size_t)TOKENS * HID * 2;
  const size_t SZ_W  = (size_t)NEXP * HID * IMD * 2;
  const size_t SZ_H  = (size_t)TOKENS * IMD * 2;
  if (ws_size < SZ_XB + 2 * SZ_W + SZ_H) return;

  char* ws = (char*)d_ws;
  unsigned short* xb  = (unsigned short*)ws;
  unsigned short* wTg = (unsigned short*)(ws + SZ_XB);
  unsigned short* wTu = (unsigned short*)(ws + SZ_XB + SZ_W);
  unsigned short* h   = (unsigned short*)(ws + SZ_XB + 2 * SZ_W);

  const int cvt_grid = (int)(((size_t)TOKENS * HID) / (256 * 8));
  convert_kernel<<<cvt_grid, 256, 0, stream>>>(x, xb, (size_t)TOKENS * HID);

  transpose_conv_kernel<<<dim3(IMD / 32, HID / 32, NEXP), dim3(32, 8), 0, stream>>>(wg, wTg, HID, IMD);
  transpose_conv_kernel<<<dim3(IMD / 32, HID / 32, NEXP), dim3(32, 8), 0, stream>>>(wu, wTu, HID, IMD);
  gemm_kernel<0, HID, IMD><<<(TOKENS / BM) * (IMD / 128), 512, 0, stream>>>(
      xb, wTg, wTu, h, nullptr, gs);

  transpose_conv_kernel<<<dim3(HID / 32, IMD / 32, NEXP), dim3(32, 8), 0, stream>>>(wd, wTg, IMD, HID);
  gemm_kernel<1, IMD, HID><<<(TOKENS / BM) * (HID / 256), 512, 0, stream>>>(
      h, wTg, nullptr, nullptr, out, gs);
}